// Round 10
// baseline (253.692 us; speedup 1.0000x reference)
//
#include <hip/hip_runtime.h>
#include <hip/hip_bf16.h>
#include <math.h>

// Problem constants
#define LQ 196      // spatial tokens (14x14)
#define NH 12       // heads
#define DH 64       // head dim
#define CC 768      // output channels
#define NPAIR 28    // 4 n * 7 t' pairs per half
#define PQ ((size_t)LQ * LQ)   // 38416
#define NW 729      // (2*14-1)^2 w rows

#define KROWS2 224  // attn: k padded to 14*16
#define LPITCH 72   // attn Ks LDS pitch (shorts)
#define WT_W 864    // Wt row width: 27 granules x 32 slots
#define AP2 456     // out A LDS pitch (shorts): 448 + 8 (228 dw = 4 mod 32: 2-way free)

// ws layout (in shorts):
//   Pm : 2 hg x 56 planes x PQ bf16 partial head-sums (8.6 MB)
//   Wt : transposed W, [w][c][i_off*32 + j_off] bf16, pads zero (2.65 MB)
//   Kb : K bf16, layout [nt][h][l<196][64] (9.6 MB)
#define PM_SHORTS ((size_t)2 * 56 * PQ)
#define WT_OFF    PM_SHORTS
#define WT_SHORTS ((size_t)2 * 768 * WT_W)
#define KB_OFF    (WT_OFF + WT_SHORTS)

typedef short short8 __attribute__((ext_vector_type(8)));
typedef float f32x4  __attribute__((ext_vector_type(4)));

__device__ __forceinline__ short f2bf(float f) {
    __hip_bfloat16 h = __float2bfloat16(f);
    return __builtin_bit_cast(short, h);
}
__device__ __forceinline__ float bf2f(short s) {
    return __builtin_bit_cast(float, (unsigned)((unsigned short)s) << 16);
}

// ---------------------------------------------------------------------------
// PREP (one launch): zero Out l=0 rows | build Wt | K -> bf16 head-major
#define ZBLK 96
#define WTBLK 1296                   // 2*768*216 threads (short4 each)
#define KBLK 4704                    // 32*12*196*16 / 256
__global__ __launch_bounds__(256) void prep_kernel(
    const float* __restrict__ K,
    const float* __restrict__ W1, const float* __restrict__ W2,
    short* __restrict__ Wt, short* __restrict__ Kb,
    float* __restrict__ Out)
{
    int b = blockIdx.x, tid = threadIdx.x;
    if (b < ZBLK) {
        int e = b * 256 + tid;                        // < 24576
        int nt = e / CC, c = e % CC;
        Out[(size_t)nt * 197 * CC + c] = 0.f;
    } else if (b < ZBLK + WTBLK) {
        int e = (b - ZBLK) * 256 + tid;               // < 331776
        int c = e % 768;
        int rest = e / 768;                           // < 432
        int slot4 = rest % 216;
        int w = rest / 216;
        const float* Wsrc = w ? W2 : W1;
        short4 v;
#pragma unroll
        for (int j = 0; j < 4; ++j) {
            int s = slot4 * 4 + j;
            int io = s >> 5, jo = s & 31;             // i_off granule, j_off slot
            float f = (jo <= 26) ? Wsrc[(size_t)(io * 27 + jo) * CC + c] : 0.f;
            ((short*)&v)[j] = f2bf(f);
        }
        *(short4*)(Wt + ((size_t)(w * 768 + c) * WT_W + slot4 * 4)) = v;
    } else {
        int loc = (b - ZBLK - WTBLK) * 256 + tid;     // < 1204224
        int c4 = loc & 15;
        int r1 = loc >> 4;
        int l  = r1 % LQ;
        int r2 = r1 / LQ;
        int h  = r2 % NH;
        int nt = r2 / NH;
        const float* s = K + (size_t)((nt * 197 + 1 + l) * NH + h) * DH + c4 * 4;
        float4 f = *(const float4*)s;
        short4 v = {f2bf(f.x), f2bf(f.y), f2bf(f.z), f2bf(f.w)};
        *(short4*)(Kb + (size_t)loc * 4) = v;
    }
}

// ---------------------------------------------------------------------------
// ATTN, head-split (unchanged from R9): block = (plane, qg, hg); 6 serial
// heads per block; writes partial head-sum plane Pm[hg][plane].
// Double-buffered K (VGPR prefetch), one barrier/head, red[] ping-pong.
__global__ __launch_bounds__(256) void attn_fused_kernel(
    const float* __restrict__ Qf, const short* __restrict__ Kb,
    short* __restrict__ Pm)
{
    int bid  = blockIdx.x;
    int xcd  = bid & 7;
    int slot = bid >> 3;                 // 0..97
    int plane = xcd + 8 * (slot / 14);   // 0..55 = hf*28 + p
    int sub   = slot % 14;
    int qg = sub % 7, hg = sub / 7;
    int p  = plane % NPAIR;
    int hf = plane / NPAIR;              // 0: (q[t+1],k[t])  1: (q[t],k[t+1])
    int n = p / 7, i = p % 7;
    int tq = hf ? i     : i + 1;
    int tk = hf ? i + 1 : i;

    __shared__ __align__(16) short Ks[2][KROWS2 * LPITCH];  // 64.5 KB
    __shared__ __align__(16) short Ps[32 * LQ];             // 12.25 KB
    __shared__ float red[2][2][2][16];                      // [h&1][strip][khalf][row]

    int tid  = threadIdx.x;
    int wave = tid >> 6, lane = tid & 63;
    int m16  = lane & 15, q4 = lane >> 4;
    int strip = wave >> 1, khalf = wave & 1;
    int tb = khalf * 7;

    const short* Kh = Kb + ((size_t)(n * 8 + tk) * NH + hg * 6) * (LQ * DH);

    int qrow = qg * 32 + strip * 16 + m16;
    int qr = (qrow < LQ) ? qrow : (LQ - 1);
    const float* qbase = Qf + (size_t)((n * 8 + tq) * 197 + 1 + qr) * (NH * DH)
                       + hg * 6 * DH + q4 * 8;

    int sr[7], sw[7];  bool sv[7];
#pragma unroll
    for (int j = 0; j < 7; ++j) {
        int e = tid + 256 * j;
        int r = e >> 3, c8 = e & 7;
        sr[j] = 8 * e;
        sw[j] = r * LPITCH + c8 * 8;
        sv[j] = (r < LQ);
    }

    {
        short8 z = {0,0,0,0,0,0,0,0};
#pragma unroll
        for (int j = 0; j < 7; ++j) {
            short8 v = sv[j] ? *(const short8*)(Kh + sr[j]) : z;
            *(short8*)&Ks[0][sw[j]] = v;
        }
    }
    short8 qa0, qa1;
    {
        float4 f0 = *(const float4*)(qbase);
        float4 f1 = *(const float4*)(qbase + 4);
        float4 f2 = *(const float4*)(qbase + 32);
        float4 f3 = *(const float4*)(qbase + 36);
        qa0[0]=f2bf(f0.x); qa0[1]=f2bf(f0.y); qa0[2]=f2bf(f0.z); qa0[3]=f2bf(f0.w);
        qa0[4]=f2bf(f1.x); qa0[5]=f2bf(f1.y); qa0[6]=f2bf(f1.z); qa0[7]=f2bf(f1.w);
        qa1[0]=f2bf(f2.x); qa1[1]=f2bf(f2.y); qa1[2]=f2bf(f2.z); qa1[3]=f2bf(f2.w);
        qa1[4]=f2bf(f3.x); qa1[5]=f2bf(f3.y); qa1[6]=f2bf(f3.z); qa1[7]=f2bf(f3.w);
    }
    __syncthreads();

    f32x4 pm[7];
#pragma unroll
    for (int t = 0; t < 7; ++t) pm[t] = (f32x4){0.f, 0.f, 0.f, 0.f};

    for (int h = 0; h < 6; ++h) {
        int cur = h & 1;

        short8 pfk[7];
        float4 pf0, pf1, pf2, pf3;
        if (h < 5) {
            const short* kn = Kh + (size_t)(h + 1) * (LQ * DH);
            short8 z = {0,0,0,0,0,0,0,0};
#pragma unroll
            for (int j = 0; j < 7; ++j)
                pfk[j] = sv[j] ? *(const short8*)(kn + sr[j]) : z;
            const float* qn = qbase + (h + 1) * DH;
            pf0 = *(const float4*)(qn);
            pf1 = *(const float4*)(qn + 4);
            pf2 = *(const float4*)(qn + 32);
            pf3 = *(const float4*)(qn + 36);
        }

        f32x4 acc[7];
#pragma unroll
        for (int t = 0; t < 7; ++t) acc[t] = (f32x4){0.f, 0.f, 0.f, 0.f};
#pragma unroll
        for (int t = 0; t < 7; ++t) {
            const short* kp = &Ks[cur][((tb + t) * 16 + m16) * LPITCH + q4 * 8];
            short8 b0 = *(const short8*)(kp);
            short8 b1 = *(const short8*)(kp + 32);
            acc[t] = __builtin_amdgcn_mfma_f32_16x16x32_bf16(qa0, b0, acc[t], 0, 0, 0);
            acc[t] = __builtin_amdgcn_mfma_f32_16x16x32_bf16(qa1, b1, acc[t], 0, 0, 0);
        }

        float v4[4] = {0.f, 0.f, 0.f, 0.f};
#pragma unroll
        for (int t = 0; t < 7; ++t) {
            int k = (tb + t) * 16 + m16;
#pragma unroll
            for (int r = 0; r < 4; ++r) {
                float pe = (k < LQ) ? __expf(acc[t][r] * 0.125f) : 0.f;
                acc[t][r] = pe;
                v4[r] += pe;
            }
        }
#pragma unroll
        for (int r = 0; r < 4; ++r) {
            v4[r] += __shfl_xor(v4[r], 1, 64);
            v4[r] += __shfl_xor(v4[r], 2, 64);
            v4[r] += __shfl_xor(v4[r], 4, 64);
            v4[r] += __shfl_xor(v4[r], 8, 64);
        }
        if (m16 == 0) {
#pragma unroll
            for (int r = 0; r < 4; ++r) red[cur][strip][khalf][q4 * 4 + r] = v4[r];
        }

        if (h < 5) {
#pragma unroll
            for (int j = 0; j < 7; ++j) *(short8*)&Ks[1 - cur][sw[j]] = pfk[j];
        }
        __syncthreads();

        float inv[4];
#pragma unroll
        for (int r = 0; r < 4; ++r)
            inv[r] = 1.0f / (12.0f * (red[cur][strip][0][q4 * 4 + r] +
                                      red[cur][strip][1][q4 * 4 + r]));
#pragma unroll
        for (int t = 0; t < 7; ++t)
#pragma unroll
            for (int r = 0; r < 4; ++r) pm[t][r] += acc[t][r] * inv[r];

        if (h < 5) {
            qa0[0]=f2bf(pf0.x); qa0[1]=f2bf(pf0.y); qa0[2]=f2bf(pf0.z); qa0[3]=f2bf(pf0.w);
            qa0[4]=f2bf(pf1.x); qa0[5]=f2bf(pf1.y); qa0[6]=f2bf(pf1.z); qa0[7]=f2bf(pf1.w);
            qa1[0]=f2bf(pf2.x); qa1[1]=f2bf(pf2.y); qa1[2]=f2bf(pf2.z); qa1[3]=f2bf(pf2.w);
            qa1[4]=f2bf(pf3.x); qa1[5]=f2bf(pf3.y); qa1[6]=f2bf(pf3.z); qa1[7]=f2bf(pf3.w);
        }
    }

#pragma unroll
    for (int t = 0; t < 7; ++t) {
        int k = (tb + t) * 16 + m16;
        if (k < LQ) {
#pragma unroll
            for (int r = 0; r < 4; ++r)
                Ps[(strip * 16 + q4 * 4 + r) * LQ + k] = f2bf(pm[t][r]);
        }
    }
    __syncthreads();

    int row0 = qg * 32;
    int rows = LQ - row0; if (rows > 32) rows = 32;
    int nb = rows * (LQ * 2);
    char* dst = (char*)(Pm + ((size_t)hg * 56 + plane) * PQ + (size_t)row0 * LQ);
    const char* sp = (const char*)Ps;
    for (int e = tid * 16; e < nb; e += 256 * 16)
        *(short8*)(dst + e) = *(const short8*)(sp + e);
}

// ---------------------------------------------------------------------------
// OUT (MFMA, transposed-W): per q, K-dim permuted to m' = (13-ki)*32 +
// (pj-kj+13) (448 slots, zeros elsewhere). B-fragment = ONE aligned b128 from
// Wt[c] + pi*32 + kb (R9: 16 scalar gathers -> 1 vector load; idx table gone).
// A: t-shifted M=32 tile staged into m'-space (zeros null B's pad slots).
// grid (196, 4): y = c-quarter, 3 c-tiles per wave.
__global__ __launch_bounds__(256) void out_mfma_kernel(
    const short* __restrict__ Pm, const short* __restrict__ Wt,
    float* __restrict__ Out)
{
    int q   = blockIdx.x;
    int yb  = blockIdx.y;
    int tid = threadIdx.x;
    int wave = tid >> 6, lane = tid & 63;
    int n16 = lane & 15, q4 = lane >> 4;

    __shared__ __align__(16) short A1s[32 * AP2];   // 28.5 KB
    __shared__ __align__(16) short A2s[32 * AP2];   // 28.5 KB

    int pi = q / 14, pj = q % 14;

    // zero-fill both A tiles (pads + unmapped slots must be 0)
    {
        short8 z = {0,0,0,0,0,0,0,0};
        for (int e = tid; e < 32 * AP2 / 8; e += 256) {
            *(short8*)&A1s[e * 8] = z;
            *(short8*)&A2s[e * 8] = z;
        }
    }
    __syncthreads();

    // scatter A = Pm[hg0] + Pm[hg1] into m'-space (t-shifted rows)
    for (int e = tid; e < 2 * 32 * LQ; e += 256) {
        int k = e % LQ;
        int r = (e / LQ) & 31;
        int hfsel = e / (32 * LQ);
        int n = r >> 3, t = r & 7;
        int pl = hfsel ? t : t - 1;
        if (pl >= 0 && pl <= 6) {
            int ki = k / 14, kj = k % 14;
            int mp = (13 - ki) * 32 + (pj - kj + 13);
            const short* s0 = Pm + (size_t)(hfsel * NPAIR + n * 7 + pl) * PQ
                                 + (size_t)q * LQ + k;
            float v = bf2f(s0[0]) + bf2f(s0[(size_t)56 * PQ]);
            (hfsel ? A2s : A1s)[r * AP2 + mp] = f2bf(v);
        }
    }
    __syncthreads();

    const short* a1p  = &A1s[n16 * AP2 + q4 * 8];
    const short* a1p2 = &A1s[(16 + n16) * AP2 + q4 * 8];
    const short* a2p  = &A2s[n16 * AP2 + q4 * 8];
    const short* a2p2 = &A2s[(16 + n16) * AP2 + q4 * 8];

    for (int i = 0; i < 3; ++i) {
        int c = (yb * 12 + wave * 3 + i) * 16 + n16;
        const short* w1p = Wt + (size_t)c * WT_W + pi * 32 + q4 * 8;
        const short* w2p = w1p + (size_t)768 * WT_W;
        f32x4 acc0 = {0.f, 0.f, 0.f, 0.f}, acc1 = {0.f, 0.f, 0.f, 0.f};

#pragma unroll
        for (int ks = 0; ks < 14; ++ks) {
            int o = ks * 32;
            short8 b1 = *(const short8*)(w1p + o);
            short8 b2 = *(const short8*)(w2p + o);
            short8 x10 = *(const short8*)(a1p + o);
            short8 x11 = *(const short8*)(a1p2 + o);
            short8 x20 = *(const short8*)(a2p + o);
            short8 x21 = *(const short8*)(a2p2 + o);
            acc0 = __builtin_amdgcn_mfma_f32_16x16x32_bf16(x10, b1, acc0, 0, 0, 0);
            acc0 = __builtin_amdgcn_mfma_f32_16x16x32_bf16(x20, b2, acc0, 0, 0, 0);
            acc1 = __builtin_amdgcn_mfma_f32_16x16x32_bf16(x11, b1, acc1, 0, 0, 0);
            acc1 = __builtin_amdgcn_mfma_f32_16x16x32_bf16(x21, b2, acc1, 0, 0, 0);
        }

#pragma unroll
        for (int mt = 0; mt < 2; ++mt) {
            f32x4 a = mt ? acc1 : acc0;
#pragma unroll
            for (int r = 0; r < 4; ++r) {
                int row = mt * 16 + q4 * 4 + r;     // = n*8 + t
                Out[(size_t)(row * 197 + 1 + q) * CC + c] = a[r];
            }
        }
    }
}

// ---------------------------------------------------------------------------
extern "C" void kernel_launch(void* const* d_in, const int* in_sizes, int n_in,
                              void* d_out, int out_size, void* d_ws, size_t ws_size,
                              hipStream_t stream) {
    const float* Q  = (const float*)d_in[0];
    const float* K  = (const float*)d_in[1];
    const float* W1 = (const float*)d_in[2];
    const float* W2 = (const float*)d_in[3];
    float* Out = (float*)d_out;
    short* Pm = (short*)d_ws;                 // 8.6 MB (2 hg partials)
    short* Wt = (short*)d_ws + WT_OFF;        // 2.65 MB transposed W
    short* Kb = (short*)d_ws + KB_OFF;        // 9.63 MB

    hipLaunchKernelGGL(prep_kernel, dim3(ZBLK + WTBLK + KBLK), dim3(256), 0, stream,
                       K, W1, W2, Wt, Kb, Out);
    hipLaunchKernelGGL(attn_fused_kernel, dim3(784), dim3(256), 0, stream,
                       Q, Kb, Pm);
    hipLaunchKernelGGL(out_mfma_kernel, dim3(196, 4), dim3(256), 0, stream,
                       Pm, Wt, Out);
}